// Round 8
// baseline (421.849 us; speedup 1.0000x reference)
//
#include <hip/hip_runtime.h>

#define N_TOK 16384
#define N_EMB 8192
#define DIM   512
#define KSPLIT 4

typedef __attribute__((ext_vector_type(8))) short bf16x8;
typedef __attribute__((ext_vector_type(4))) float f32x4;
typedef unsigned short u16;

__device__ __forceinline__ u16 f2bf(float f) {
    unsigned u = __float_as_uint(f);
    u += 0x7fffu + ((u >> 16) & 1u);
    return (u16)(u >> 16);
}
__device__ __forceinline__ float bf2f(u16 h) {
    return __uint_as_float(((unsigned)h) << 16);
}

__device__ __forceinline__ void gload16(const void* g, void* l) {
    __builtin_amdgcn_global_load_lds(
        (const __attribute__((address_space(1))) unsigned int*)g,
        (__attribute__((address_space(3))) unsigned int*)l, 16, 0, 0);
}

// ---- prep: interleaved split layout: [row][16 kblocks][32 hi | 32 lo] bf16 (128 B lines)
__global__ void prep_x_kernel(const float* __restrict__ x, u16* __restrict__ xint) {
    const int tid = threadIdx.x, lane = tid & 63, wvi = tid >> 6;
    const int row = blockIdx.x * 4 + wvi;
    const float* src = x + (size_t)row * DIM + lane * 8;
    float4 v0 = *(const float4*)src;
    float4 v1 = *(const float4*)(src + 4);
    float vv[8] = {v0.x, v0.y, v0.z, v0.w, v1.x, v1.y, v1.z, v1.w};
    bf16x8 hv, lv;
#pragma unroll
    for (int i = 0; i < 8; ++i) {
        u16 h = f2bf(vv[i]);
        hv[i] = (short)h;
        lv[i] = (short)f2bf(vv[i] - bf2f(h));
    }
    u16* dst = xint + (size_t)row * 1024 + (lane >> 2) * 64 + (lane & 3) * 8;
    *(bf16x8*)dst = hv;
    *(bf16x8*)(dst + 32) = lv;
}

__global__ void prep_w_kernel(const float* __restrict__ w, u16* __restrict__ wint,
                              float* __restrict__ wsq) {
    const int tid = threadIdx.x, lane = tid & 63, wvi = tid >> 6;
    const int row = blockIdx.x * 4 + wvi;
    const float* src = w + (size_t)row * DIM + lane * 8;
    float4 v0 = *(const float4*)src;
    float4 v1 = *(const float4*)(src + 4);
    float vv[8] = {v0.x, v0.y, v0.z, v0.w, v1.x, v1.y, v1.z, v1.w};
    bf16x8 hv, lv;
    float s = 0.f;
#pragma unroll
    for (int i = 0; i < 8; ++i) {
        u16 h = f2bf(vv[i]);
        hv[i] = (short)h;
        lv[i] = (short)f2bf(vv[i] - bf2f(h));
        s += vv[i] * vv[i];
    }
    u16* dst = wint + (size_t)row * 1024 + (lane >> 2) * 64 + (lane & 3) * 8;
    *(bf16x8*)dst = hv;
    *(bf16x8*)(dst + 32) = lv;
#pragma unroll
    for (int off = 1; off < 64; off <<= 1) s += __shfl_xor(s, off);
    if (lane == 0) wsq[row] = s;
}

// ---- main: 3-pass split-bf16 GEMM, 16x16x32 frags, TRIPLE-buffered BK=32,
//      in-wave frag prefetch (B+A0 of tile t+1 read during tile t's MFMA).
// Block: 512 thr (8 waves as 4 wm x 2 wn), tile 256 rows x 128 codes. 1 block/CU.
// LDS buf (48 KiB): A[256][64 u16] | B[128][64 u16]; x3 = 144 KiB.
// Swizzle (proven): 16B granule g of row r at position g ^ (r&7).
#define MFMA3(d, ah, al, bh, bl)                                              \
    do {                                                                      \
        d = __builtin_amdgcn_mfma_f32_16x16x32_bf16(ah, bh, d, 0, 0, 0);      \
        d = __builtin_amdgcn_mfma_f32_16x16x32_bf16(ah, bl, d, 0, 0, 0);      \
        d = __builtin_amdgcn_mfma_f32_16x16x32_bf16(al, bh, d, 0, 0, 0);      \
    } while (0)

__global__ __launch_bounds__(512, 1)
void gemm_argmin_kernel(const u16* __restrict__ xint, const u16* __restrict__ wint,
                        const float* __restrict__ wsq,
                        float* __restrict__ wsval, int* __restrict__ wsidx) {
    __shared__ u16 sm[3][24576];   // 144 KiB
    const int tid = threadIdx.x;
    const int lane = tid & 63, wv = tid >> 6;   // wv 0..7
    const int wm = wv >> 1, wn = wv & 1;
    const int RB = blockIdx.x * 256;
    const int CB = blockIdx.y * 2048;
    const int l15 = lane & 15, l4 = lane >> 4;

    const int sg = (lane & 7) ^ ((lane >> 3) & 7);   // pre-swizzled source granule
    const int srow = lane >> 3;

    float runv[16];
    int   runi[16];
#pragma unroll
    for (int e = 0; e < 16; ++e) { runv[e] = 3.4e38f; runi[e] = 0; }

    // read-side row bases
    const int rA0 = wm * 64 + l15;   // + mi*16
    const int rB0 = wn * 64 + l15;   // + ni*16

    auto stage = [&](int t) {
        u16* buf = &sm[t % 3][0];
        const int kb = t & 15;
        const int cb = CB + (t >> 4) * 128;
#pragma unroll
        for (int j = 0; j < 4; ++j) {              // A: 32 segs of 8 rows
            int seg = wv * 4 + j;
            int r = seg * 8 + srow;
            gload16(xint + (size_t)(RB + r) * 1024 + kb * 64 + sg * 8, buf + seg * 512);
        }
#pragma unroll
        for (int j = 0; j < 2; ++j) {              // B: 16 segs
            int seg = wv * 2 + j;
            int r = seg * 8 + srow;
            gload16(wint + (size_t)(cb + r) * 1024 + kb * 64 + sg * 8, buf + 16384 + seg * 512);
        }
    };

    // fragment readers (proven zero-conflict pattern)
#define READ_A(buf, mi, h, l)                                                  \
    {                                                                          \
        int r_ = rA0 + (mi) * 16;                                              \
        int off_ = r_ * 128 + ((l4 ^ (r_ & 7)) << 4);                          \
        h = *(const bf16x8*)((const char*)(buf) + off_);                       \
        l = *(const bf16x8*)((const char*)(buf) + (off_ ^ 64));                \
    }
#define READ_B(buf, ni, h, l)                                                  \
    {                                                                          \
        int r_ = rB0 + (ni) * 16;                                              \
        int off_ = r_ * 128 + ((l4 ^ (r_ & 7)) << 4);                          \
        h = *(const bf16x8*)((const char*)(buf) + 32768 + off_);               \
        l = *(const bf16x8*)((const char*)(buf) + 32768 + (off_ ^ 64));        \
    }

    // prologue: tiles 0,1 staged; prefetch frags of tile 0
    stage(0);
    stage(1);
    asm volatile("s_waitcnt vmcnt(6)" ::: "memory");  // stage(0) landed
    __builtin_amdgcn_s_barrier();

    bf16x8 pbh[4], pbl[4], pah, pal;
    {
        const u16* b0 = &sm[0][0];
#pragma unroll
        for (int ni = 0; ni < 4; ++ni) { READ_B(b0, ni, pbh[ni], pbl[ni]); }
        READ_A(b0, 0, pah, pal);
    }

    f32x4 acc[4][4];
    float wq[4];
    bf16x8 nbh[4] = {}, nbl[4] = {}, nah = {}, nal = {};

    for (int t = 0; t < 256; ++t) {
        const u16* bufc = &sm[t % 3][0];

        if ((t & 15) == 0) {
            const int c0 = CB + (t >> 4) * 128 + wn * 64;
#pragma unroll
            for (int ni = 0; ni < 4; ++ni)
                wq[ni] = wsq[c0 + ni * 16 + l15];     // issued before stage -> vmcnt-safe
#pragma unroll
            for (int mi = 0; mi < 4; ++mi)
#pragma unroll
                for (int ni = 0; ni < 4; ++ni)
                    acc[mi][ni] = (f32x4){0.f, 0.f, 0.f, 0.f};
        }

        if (t < 254) stage(t + 2);   // buf[(t+2)%3] free since BAR-B of step t-1

        bf16x8 ah1, al1, ah2, al2, ah3, al3;
        READ_A(bufc, 1, ah1, al1);
        READ_A(bufc, 2, ah2, al2);
        READ_A(bufc, 3, ah3, al3);

        // MFMA cluster mi=0 on prefetched frags (no LDS wait)
        __builtin_amdgcn_s_setprio(1);
#pragma unroll
        for (int ni = 0; ni < 4; ++ni) { MFMA3(acc[0][ni], pah, pal, pbh[ni], pbl[ni]); }
        __builtin_amdgcn_s_setprio(0);

        // stage(t+1) landed -> prefetch tile t+1 fragments during remaining MFMA
        if (t < 254) asm volatile("s_waitcnt vmcnt(6)" ::: "memory");
        else         asm volatile("s_waitcnt vmcnt(0)" ::: "memory");
        __builtin_amdgcn_sched_barrier(0);
        __builtin_amdgcn_s_barrier();             // BAR-A: everyone's stage(t+1) landed

        if (t < 255) {
            const u16* bufn = &sm[(t + 1) % 3][0];
#pragma unroll
            for (int ni = 0; ni < 4; ++ni) { READ_B(bufn, ni, nbh[ni], nbl[ni]); }
            READ_A(bufn, 0, nah, nal);
        }

        __builtin_amdgcn_s_setprio(1);
#pragma unroll
        for (int ni = 0; ni < 4; ++ni) { MFMA3(acc[1][ni], ah1, al1, pbh[ni], pbl[ni]); }
#pragma unroll
        for (int ni = 0; ni < 4; ++ni) { MFMA3(acc[2][ni], ah2, al2, pbh[ni], pbl[ni]); }
#pragma unroll
        for (int ni = 0; ni < 4; ++ni) { MFMA3(acc[3][ni], ah3, al3, pbh[ni], pbl[ni]); }
        __builtin_amdgcn_s_setprio(0);

        if ((t & 15) == 15) {
            // chunk epilogue: score = wsq - 2*S ; streaming argmin
            const int cb = CB + (t >> 4) * 128;
#pragma unroll
            for (int mi = 0; mi < 4; ++mi)
#pragma unroll
                for (int ni = 0; ni < 4; ++ni) {
                    int idx = cb + wn * 64 + ni * 16 + l15;
#pragma unroll
                    for (int r = 0; r < 4; ++r) {
                        float sc = wq[ni] - 2.0f * acc[mi][ni][r];
                        int e = mi * 4 + r;
                        if (sc < runv[e]) { runv[e] = sc; runi[e] = idx; }
                    }
                }
        }

        // my tile-t reads done (A-reads older than the 10 outstanding prefetches)
        if (t < 255) asm volatile("s_waitcnt lgkmcnt(10)" ::: "memory");
        else         asm volatile("s_waitcnt lgkmcnt(0)" ::: "memory");
        __builtin_amdgcn_sched_barrier(0);
        __builtin_amdgcn_s_barrier();             // BAR-B: buf[t%3] free for stage(t+3)

        pah = nah; pal = nal;
#pragma unroll
        for (int ni = 0; ni < 4; ++ni) { pbh[ni] = nbh[ni]; pbl[ni] = nbl[ni]; }
    }

    asm volatile("s_waitcnt vmcnt(0) lgkmcnt(0)" ::: "memory");
    __builtin_amdgcn_s_barrier();

    // cross-lane argmin reduce (16-lane groups share rows, own cols)
    float* mv  = (float*)&sm[0][0];                 // [2][256]
    int*   mi_ = (int*)((char*)&sm[0][0] + 2048);   // [2][256]
#pragma unroll
    for (int e = 0; e < 16; ++e) {
        float v = runv[e];
        int   ix = runi[e];
#pragma unroll
        for (int off = 1; off < 16; off <<= 1) {
            float ov = __shfl_xor(v, off);
            int   oi = __shfl_xor(ix, off);
            if (ov < v || (ov == v && oi < ix)) { v = ov; ix = oi; }
        }
        if (l15 == 0) {
            int rl = wm * 64 + (e >> 2) * 16 + l4 * 4 + (e & 3);
            mv[wn * 256 + rl]  = v;
            mi_[wn * 256 + rl] = ix;
        }
    }
    __syncthreads();
    if (tid < 256) {
        float v0 = mv[tid];       int i0 = mi_[tid];
        float v1 = mv[256 + tid]; int i1 = mi_[256 + tid];
        if (v1 < v0 || (v1 == v0 && i1 < i0)) { v0 = v1; i0 = i1; }
        wsval[(size_t)(RB + tid) * KSPLIT + blockIdx.y] = v0;
        wsidx[(size_t)(RB + tid) * KSPLIT + blockIdx.y] = i0;
    }
}

// ---------------- merge ksplits + gather + loss partials ----------------
__global__ void gather_loss_kernel(const float* __restrict__ w, const float* __restrict__ x,
                                   const float* __restrict__ wsval, const int* __restrict__ wsidx,
                                   float* __restrict__ out, float* __restrict__ lossp) {
    const int tid = threadIdx.x, lane = tid & 63, wvi = tid >> 6;
    const int t = blockIdx.x * 4 + wvi;
    int bi = 0;
    if (lane == 0) {
        float bv = wsval[(size_t)t * KSPLIT];
        bi = wsidx[(size_t)t * KSPLIT];
#pragma unroll
        for (int ks = 1; ks < KSPLIT; ++ks) {
            float v = wsval[(size_t)t * KSPLIT + ks];
            int  ix = wsidx[(size_t)t * KSPLIT + ks];
            if (v < bv || (v == bv && ix < bi)) { bv = v; bi = ix; }
        }
    }
    bi = __shfl(bi, 0);
    const float* wr = w + (size_t)bi * DIM;
    const float* xr = x + (size_t)t * DIM;
    float* orow = out + (size_t)t * DIM;
    float s = 0.f;
#pragma unroll
    for (int j = 0; j < 2; ++j) {
        int d = j * 256 + lane * 4;
        float4 a = *(const float4*)(wr + d);
        float4 b = *(const float4*)(xr + d);
        *(float4*)(orow + d) = a;
        float d0 = a.x - b.x, d1 = a.y - b.y, d2 = a.z - b.z, d3 = a.w - b.w;
        s += d0 * d0 + d1 * d1 + d2 * d2 + d3 * d3;
    }
#pragma unroll
    for (int off = 1; off < 64; off <<= 1) s += __shfl_xor(s, off);
    __shared__ float ls[4];
    if (lane == 0) ls[wvi] = s;
    __syncthreads();
    if (tid == 0) lossp[blockIdx.x] = ls[0] + ls[1] + ls[2] + ls[3];
}

// ---------------- deterministic final loss reduce ----------------
__global__ void loss_final_kernel(const float* __restrict__ lossp, float* __restrict__ out) {
    __shared__ float red[256];
    float s = 0.f;
    for (int i = threadIdx.x; i < N_TOK / 4; i += 256) s += lossp[i];
    red[threadIdx.x] = s;
    __syncthreads();
    for (int st = 128; st > 0; st >>= 1) {
        if (threadIdx.x < st) red[threadIdx.x] += red[threadIdx.x + st];
        __syncthreads();
    }
    // vq_loss = (1 + BETA) * mean((q - x)^2)
    if (threadIdx.x == 0) out[(size_t)N_TOK * DIM] = red[0] * (1.25f / 8388608.f);
}

extern "C" void kernel_launch(void* const* d_in, const int* in_sizes, int n_in,
                              void* d_out, int out_size, void* d_ws, size_t ws_size,
                              hipStream_t stream) {
    const float* x = (const float*)d_in[0];   // [16384,512]
    const float* w = (const float*)d_in[1];   // [8192,512]
    float* out = (float*)d_out;               // 16384*512 + 1

    char* W = (char*)d_ws;
    u16*   xint  = (u16*)(W);                        // 32 MiB
    u16*   wint  = (u16*)(W + 33554432);             // 16 MiB
    float* wsq   = (float*)(W + 50331648);           // 32 KiB
    float* wsval = (float*)(W + 50364416);           // 256 KiB
    int*   wsidx = (int*)  (W + 50626560);           // 256 KiB
    float* lossp = (float*)(W + 50888704);           // 16 KiB

    prep_x_kernel<<<N_TOK / 4, 256, 0, stream>>>(x, xint);
    prep_w_kernel<<<N_EMB / 4, 256, 0, stream>>>(w, wint, wsq);
    dim3 g(N_TOK / 256, KSPLIT);
    gemm_argmin_kernel<<<g, 512, 0, stream>>>(xint, wint, wsq, wsval, wsidx);
    gather_loss_kernel<<<N_TOK / 4, 256, 0, stream>>>(w, x, wsval, wsidx, out, lossp);
    loss_final_kernel<<<1, 256, 0, stream>>>(lossp, out);
}